// Round 8
// baseline (127.437 us; speedup 1.0000x reference)
//
#include <hip/hip_runtime.h>

typedef unsigned short u16;
typedef float f32x4 __attribute__((ext_vector_type(4)));
typedef __bf16 bf16x8 __attribute__((ext_vector_type(8)));
typedef unsigned int u32x4 __attribute__((ext_vector_type(4)));
typedef u16 u16x4 __attribute__((ext_vector_type(4)));
typedef u16 u16x8 __attribute__((ext_vector_type(8)));

static __device__ __forceinline__ u16 f2bf(float f) {
  union { __bf16 h; u16 u; } c;
  c.h = (__bf16)f;
  return c.u;
}

static __device__ __forceinline__ void gload_lds16(const void* g, void* l) {
  __builtin_amdgcn_global_load_lds(
      (const __attribute__((address_space(1))) unsigned int*)g,
      (__attribute__((address_space(3))) unsigned int*)l, 16, 0, 0);
}

// ---------------- fp32 -> bf16 convert ----------------
__global__ __launch_bounds__(256) void cvt_f32_bf16(const float* __restrict__ in,
                                                    u16* __restrict__ out, int n4) {
  int i = blockIdx.x * 256 + threadIdx.x;
  if (i < n4) {
    f32x4 v = *((const f32x4*)in + i);
    u16x4 o;
    o[0] = f2bf(v[0]); o[1] = f2bf(v[1]); o[2] = f2bf(v[2]); o[3] = f2bf(v[3]);
    *((u16x4*)out + i) = o;
  }
}

// ---------------- GEMM: C[M,N] = A[M,K] * B[N,K]^T (bf16 in, fp32 acc) ----------------
template<int OUT_BF16>
__global__ __launch_bounds__(256) void gemm_nt(const u16* __restrict__ A,
                                               const u16* __restrict__ B,
                                               void* __restrict__ Cp,
                                               int M, int N, int K) {
  __shared__ __align__(16) u16 lA[128 * 64];
  __shared__ __align__(16) u16 lB[128 * 64];
  const int tid = threadIdx.x;
  const int lane = tid & 63;
  const int wave = tid >> 6;
  const int wm = wave >> 1, wn = wave & 1;
  const int l15 = lane & 15, lg = lane >> 4;
  const int bm = blockIdx.y * 128, bn = blockIdx.x * 128;

  f32x4 acc[4][4];
#pragma unroll
  for (int i = 0; i < 4; ++i)
#pragma unroll
    for (int j = 0; j < 4; ++j) acc[i][j] = (f32x4){0.f, 0.f, 0.f, 0.f};

  const u16* Ag[4];
  const u16* Bg[4];
#pragma unroll
  for (int it = 0; it < 4; ++it) {
    const int s = it * 256 + tid;
    const int row = s >> 3, g = s & 7;
    const int gsw = g ^ (row & 7);  // inverse swizzle on global source
    Ag[it] = A + (size_t)(bm + row) * K + gsw * 8;
    Bg[it] = B + (size_t)(bn + row) * K + gsw * 8;
  }

  for (int k0 = 0; k0 < K; k0 += 64) {
#pragma unroll
    for (int it = 0; it < 4; ++it) {
      gload_lds16(Ag[it] + k0, (u16*)lA + (size_t)(it * 256 + tid) * 8);
      gload_lds16(Bg[it] + k0, (u16*)lB + (size_t)(it * 256 + tid) * 8);
    }
    __syncthreads();
#pragma unroll
    for (int kk = 0; kk < 2; ++kk) {
      bf16x8 af[4], bfv[4];
#pragma unroll
      for (int mf = 0; mf < 4; ++mf) {
        const int row = wm * 64 + mf * 16 + l15;
        af[mf] = *(const bf16x8*)((const char*)lA + row * 128 +
                                  ((kk * 64 + lg * 16) ^ ((row & 7) << 4)));
      }
#pragma unroll
      for (int nf = 0; nf < 4; ++nf) {
        const int row = wn * 64 + nf * 16 + l15;
        bfv[nf] = *(const bf16x8*)((const char*)lB + row * 128 +
                                   ((kk * 64 + lg * 16) ^ ((row & 7) << 4)));
      }
#pragma unroll
      for (int mf = 0; mf < 4; ++mf)
#pragma unroll
        for (int nf = 0; nf < 4; ++nf)
          acc[mf][nf] = __builtin_amdgcn_mfma_f32_16x16x32_bf16(af[mf], bfv[nf], acc[mf][nf], 0, 0, 0);
    }
    __syncthreads();
  }

#pragma unroll
  for (int mf = 0; mf < 4; ++mf) {
#pragma unroll
    for (int r = 0; r < 4; ++r) {
      const int row = bm + wm * 64 + mf * 16 + lg * 4 + r;
#pragma unroll
      for (int nf = 0; nf < 4; ++nf) {
        const int col = bn + wn * 64 + nf * 16 + l15;
        const float v = acc[mf][nf][r];
        if (OUT_BF16) ((u16*)Cp)[(size_t)row * N + col] = f2bf(v);
        else          ((float*)Cp)[(size_t)row * N + col] = v;
      }
    }
  }
}

// ---------------- transpose V: qkv v-part [b,t,h,d] -> vt[bh][d][t] ----------------
__global__ __launch_bounds__(256) void transpose_v(const u16* __restrict__ qkv,
                                                   u16* __restrict__ vt) {
  constexpr int T = 2048, C3 = 3072, D = 64;
  __shared__ u16 lt[64 * 65];
  const int t0 = blockIdx.x * 64;
  const int bh = blockIdx.y;
  const int b = bh >> 4, h = bh & 15;
  const int tid = threadIdx.x;
#pragma unroll
  for (int it = 0; it < 2; ++it) {
    const int c = tid + it * 256;
    const int tr = c >> 3, d0 = (c & 7) * 8;
    u32x4 v = *(const u32x4*)&qkv[((size_t)b * T + t0 + tr) * C3 + 2048 + h * D + d0];
    const u16* pv = (const u16*)&v;
#pragma unroll
    for (int e = 0; e < 8; ++e) lt[tr * 65 + d0 + e] = pv[e];
  }
  __syncthreads();
#pragma unroll
  for (int it = 0; it < 2; ++it) {
    const int c = tid + it * 256;
    const int d = c >> 3, toff = (c & 7) * 8;
    u16x8 tmp;
#pragma unroll
    for (int e = 0; e < 8; ++e) tmp[e] = lt[(toff + e) * 65 + d];
    *(u16x8*)&vt[((size_t)bh * D + d) * T + t0 + toff] = tmp;
  }
}

// online softmax for one tile (swapped layout: lane owns q-row w*16+l15;
// s holds kv=nf*16+lg*4+r). Converts s -> p in place, updates m,l,o.
static __device__ __forceinline__ void online_sm(f32x4 (&s)[4], bool diag,
                                                 int lg, int l15, int w,
                                                 float qscale, float& m, float& l,
                                                 f32x4 (&o)[4]) {
  const int ql = w * 16 + l15;
#pragma unroll
  for (int nf = 0; nf < 4; ++nf)
#pragma unroll
    for (int r = 0; r < 4; ++r) {
      float v = s[nf][r] * qscale;
      if (diag && (nf * 16 + lg * 4 + r > ql)) v = -1.0e30f;
      s[nf][r] = v;
    }
  float t0a = fmaxf(fmaxf(s[0][0], s[0][1]), fmaxf(s[0][2], s[0][3]));
  float t1a = fmaxf(fmaxf(s[1][0], s[1][1]), fmaxf(s[1][2], s[1][3]));
  float t2a = fmaxf(fmaxf(s[2][0], s[2][1]), fmaxf(s[2][2], s[2][3]));
  float t3a = fmaxf(fmaxf(s[3][0], s[3][1]), fmaxf(s[3][2], s[3][3]));
  float pmax = fmaxf(fmaxf(t0a, t1a), fmaxf(t2a, t3a));
  pmax = fmaxf(pmax, __shfl_xor(pmax, 16));
  pmax = fmaxf(pmax, __shfl_xor(pmax, 32));
  if (!__all(pmax <= m)) {
    const float mnew = fmaxf(m, pmax);
    const float fct = __builtin_amdgcn_exp2f(m - mnew);
    m = mnew;
    l *= fct;
#pragma unroll
    for (int r = 0; r < 4; ++r) {
      const float fr = __shfl(fct, lg * 4 + r);
#pragma unroll
      for (int nf = 0; nf < 4; ++nf) o[nf][r] *= fr;
    }
  }
#pragma unroll
  for (int nf = 0; nf < 4; ++nf)
#pragma unroll
    for (int r = 0; r < 4; ++r) s[nf][r] = __builtin_amdgcn_exp2f(s[nf][r] - m);
  float s0a = (s[0][0] + s[0][1]) + (s[0][2] + s[0][3]);
  float s1a = (s[1][0] + s[1][1]) + (s[1][2] + s[1][3]);
  float s2a = (s[2][0] + s[2][1]) + (s[2][2] + s[2][3]);
  float s3a = (s[3][0] + s[3][1]) + (s[3][2] + s[3][3]);
  float psum = (s0a + s1a) + (s2a + s3a);
  psum += __shfl_xor(psum, 16);
  psum += __shfl_xor(psum, 32);
  l += psum;
}

// ---------------- flash attention fwd (causal), bf16 MFMA ----------------
// Dual-q-tile shared-KV: block handles q-tiles (pi, 31-pi) in ONE kv sweep
// kt=0..31-pi; tile A (pi) active while kt<=pi. Each K/V frag read feeds both
// tiles' MFMAs; 32-pi barrier-iters/block. Complementary block decode puts
// pi and 15-pi on the same CU -> constant 49 iters/CU. Swapped QK^T softmax,
// THR=0 defer-max, dbuf K/V, 2-deep prefetch, XCD-aware decode.
__global__ __launch_bounds__(256, 2) void attn_fwd(const u16* __restrict__ qkv,
                                                   const u16* __restrict__ vt,
                                                   u16* __restrict__ y) {
  constexpr int T = 2048, C = 1024, C3 = 3072, D = 64, NQ = 32;
  __shared__ __align__(16) u16 lK[2][64 * 64];
  __shared__ __align__(16) u16 lV[2][64 * 64];
  __shared__ __align__(16) u16 lP[2][4 * 16 * 64];  // [tile][wave 2KB]
  const int tid = threadIdx.x, lane = tid & 63, w = tid >> 6;
  const int l15 = lane & 15, lg = lane >> 4;

  // XCD-aware + complementary decode: xcd c hosts bh in [4c,4c+4);
  // CU-sharing blocks (bid, bid+256) get pair-indices pi and 15-pi.
  const int bid = blockIdx.x;
  const int xcd = bid & 7, slot = bid >> 3;
  const int half = slot >> 5, s5 = slot & 31;
  const int bh = xcd * 4 + (s5 >> 4) + 2 * half;
  const int pp = s5 & 15;
  const int pi = half ? (15 - pp) : pp;
  const int b = bh >> 4, h = bh & 15;
  const int qa = pi, qb = NQ - 1 - pi;

  // staging mapping (two 16B chunks per thread per tile)
  const int r0 = tid >> 3, off0 = (tid & 7) * 8;
  const int r1 = (tid + 256) >> 3, off1 = off0;
  const int sb0 = (off0 * 2) ^ ((r0 & 7) << 4);
  const int sb1 = (off1 * 2) ^ ((r1 & 7) << 4);
  const u16* Kbase = qkv + (size_t)b * T * C3 + C + h * D;
  const u16* Vbase = vt + (size_t)bh * D * T;

  const float qscale = 0.125f * 1.44269504088896f;  // scale * log2(e)

  const size_t qoffA = ((size_t)b * T + qa * 64 + w * 16 + l15) * C3 + h * D;
  const size_t qoffB = ((size_t)b * T + qb * 64 + w * 16 + l15) * C3 + h * D;
  const bf16x8 aqA0 = *(const bf16x8*)&qkv[qoffA + lg * 8];
  const bf16x8 aqA1 = *(const bf16x8*)&qkv[qoffA + 32 + lg * 8];
  const bf16x8 aqB0 = *(const bf16x8*)&qkv[qoffB + lg * 8];
  const bf16x8 aqB1 = *(const bf16x8*)&qkv[qoffB + 32 + lg * 8];

  float mA = -1.0e30f, lA2 = 0.f, mB = -1.0e30f, lB2 = 0.f;
  f32x4 oA[4], oB[4];
#pragma unroll
  for (int nf = 0; nf < 4; ++nf) {
    oA[nf] = (f32x4){0.f, 0.f, 0.f, 0.f};
    oB[nf] = (f32x4){0.f, 0.f, 0.f, 0.f};
  }

  // prologue: tile 0 -> buf0; tile 1 -> regs (qb >= 16, so both exist)
  u32x4 rk0 = *(const u32x4*)(Kbase + (size_t)r0 * C3 + off0);
  u32x4 rk1 = *(const u32x4*)(Kbase + (size_t)r1 * C3 + off1);
  u32x4 rv0 = *(const u32x4*)(Vbase + (size_t)r0 * T + off0);
  u32x4 rv1 = *(const u32x4*)(Vbase + (size_t)r1 * T + off1);
  *(u32x4*)&lK[0][(r0 * 128 + sb0) >> 1] = rk0;
  *(u32x4*)&lK[0][(r1 * 128 + sb1) >> 1] = rk1;
  *(u32x4*)&lV[0][(r0 * 128 + sb0) >> 1] = rv0;
  *(u32x4*)&lV[0][(r1 * 128 + sb1) >> 1] = rv1;
  rk0 = *(const u32x4*)(Kbase + (size_t)(64 + r0) * C3 + off0);
  rk1 = *(const u32x4*)(Kbase + (size_t)(64 + r1) * C3 + off1);
  rv0 = *(const u32x4*)(Vbase + (size_t)r0 * T + 64 + off0);
  rv1 = *(const u32x4*)(Vbase + (size_t)r1 * T + 64 + off1);

  for (int kt = 0; kt <= qb; ++kt) {
    const int cur = kt & 1;
    __syncthreads();  // buf[cur] visible; buf[cur^1] readers drained
    if (kt < qb) {
      *(u32x4*)&lK[cur ^ 1][(r0 * 128 + sb0) >> 1] = rk0;
      *(u32x4*)&lK[cur ^ 1][(r1 * 128 + sb1) >> 1] = rk1;
      *(u32x4*)&lV[cur ^ 1][(r0 * 128 + sb0) >> 1] = rv0;
      *(u32x4*)&lV[cur ^ 1][(r1 * 128 + sb1) >> 1] = rv1;
      if (kt + 1 < qb) {
        const int kn = (kt + 2) * 64;
        rk0 = *(const u32x4*)(Kbase + (size_t)(kn + r0) * C3 + off0);
        rk1 = *(const u32x4*)(Kbase + (size_t)(kn + r1) * C3 + off1);
        rv0 = *(const u32x4*)(Vbase + (size_t)r0 * T + kn + off0);
        rv1 = *(const u32x4*)(Vbase + (size_t)r1 * T + kn + off1);
      }
    }
    const u16* Kc = lK[cur];
    const u16* Vc = lV[cur];
    const bool actA = (kt <= qa);

    // S^T = K Q^T for both tiles, sharing K-frag reads
    f32x4 sA[4], sB[4];
#pragma unroll
    for (int nf = 0; nf < 4; ++nf) sB[nf] = (f32x4){0.f, 0.f, 0.f, 0.f};
    if (actA) {
#pragma unroll
      for (int nf = 0; nf < 4; ++nf) sA[nf] = (f32x4){0.f, 0.f, 0.f, 0.f};
    }
    __builtin_amdgcn_s_setprio(1);
#pragma unroll
    for (int nf = 0; nf < 4; ++nf) {
      const int row = nf * 16 + l15;
      const int x = (row & 7) << 4;
      bf16x8 bk0 = *(const bf16x8*)&Kc[(row * 128 + ((lg * 16) ^ x)) >> 1];
      bf16x8 bk1 = *(const bf16x8*)&Kc[(row * 128 + ((64 + lg * 16) ^ x)) >> 1];
      sB[nf] = __builtin_amdgcn_mfma_f32_16x16x32_bf16(bk0, aqB0, sB[nf], 0, 0, 0);
      sB[nf] = __builtin_amdgcn_mfma_f32_16x16x32_bf16(bk1, aqB1, sB[nf], 0, 0, 0);
      if (actA) {
        sA[nf] = __builtin_amdgcn_mfma_f32_16x16x32_bf16(bk0, aqA0, sA[nf], 0, 0, 0);
        sA[nf] = __builtin_amdgcn_mfma_f32_16x16x32_bf16(bk1, aqA1, sA[nf], 0, 0, 0);
      }
    }
    __builtin_amdgcn_s_setprio(0);

    // softmax (B always, A if active); s -> p in place
    online_sm(sB, kt == qb, lg, l15, w, qscale, mB, lB2, oB);
    if (actA) online_sm(sA, kt == qa, lg, l15, w, qscale, mA, lA2, oA);

    // P-stores (per-wave regions, same-wave RAW -> no barrier)
    char* lPB = (char*)lP[1] + w * 2048;
    char* lPA = (char*)lP[0] + w * 2048;
#pragma unroll
    for (int nf = 0; nf < 4; ++nf) {
      u16x4 pk;
      pk[0] = f2bf(sB[nf][0]); pk[1] = f2bf(sB[nf][1]);
      pk[2] = f2bf(sB[nf][2]); pk[3] = f2bf(sB[nf][3]);
      *(u16x4*)(lPB + l15 * 128 + ((nf * 32 + lg * 8) ^ ((l15 & 7) << 4))) = pk;
    }
    if (actA) {
#pragma unroll
      for (int nf = 0; nf < 4; ++nf) {
        u16x4 pk;
        pk[0] = f2bf(sA[nf][0]); pk[1] = f2bf(sA[nf][1]);
        pk[2] = f2bf(sA[nf][2]); pk[3] = f2bf(sA[nf][3]);
        *(u16x4*)(lPA + l15 * 128 + ((nf * 32 + lg * 8) ^ ((l15 & 7) << 4))) = pk;
      }
    }

    // O += P V, sharing V-frag reads
    __builtin_amdgcn_s_setprio(1);
#pragma unroll
    for (int sj = 0; sj < 2; ++sj) {
      bf16x8 apB = *(const bf16x8*)(lPB + l15 * 128 + ((sj * 64 + lg * 16) ^ ((l15 & 7) << 4)));
      bf16x8 apA;
      if (actA) apA = *(const bf16x8*)(lPA + l15 * 128 + ((sj * 64 + lg * 16) ^ ((l15 & 7) << 4)));
#pragma unroll
      for (int nf = 0; nf < 4; ++nf) {
        const int d = nf * 16 + l15;
        bf16x8 bv = *(const bf16x8*)&Vc[(d * 128 + ((sj * 64 + lg * 16) ^ ((d & 7) << 4))) >> 1];
        oB[nf] = __builtin_amdgcn_mfma_f32_16x16x32_bf16(apB, bv, oB[nf], 0, 0, 0);
        if (actA) oA[nf] = __builtin_amdgcn_mfma_f32_16x16x32_bf16(apA, bv, oA[nf], 0, 0, 0);
      }
    }
    __builtin_amdgcn_s_setprio(0);
  }

  // epilogue: both tiles
#pragma unroll
  for (int r = 0; r < 4; ++r) {
    const float liA = __builtin_amdgcn_rcpf(__shfl(lA2, lg * 4 + r));
    const float liB = __builtin_amdgcn_rcpf(__shfl(lB2, lg * 4 + r));
    const int rowA = qa * 64 + w * 16 + lg * 4 + r;
    const int rowB = qb * 64 + w * 16 + lg * 4 + r;
#pragma unroll
    for (int nf = 0; nf < 4; ++nf) {
      const int col = h * D + nf * 16 + l15;
      y[((size_t)b * T + rowA) * C + col] = f2bf(oA[nf][r] * liA);
      y[((size_t)b * T + rowB) * C + col] = f2bf(oB[nf][r] * liB);
    }
  }
}

extern "C" void kernel_launch(void* const* d_in, const int* in_sizes, int n_in,
                              void* d_out, int out_size, void* d_ws, size_t ws_size,
                              hipStream_t stream) {
  const float* x = (const float*)d_in[0];
  const float* Wqkv = (const float*)d_in[1];
  const float* Wproj = (const float*)d_in[2];
  float* out = (float*)d_out;

  constexpr int B = 2, T = 2048, C = 1024, C3 = 3072, H = 16, D = 64;
  constexpr int M = B * T;  // 4096

  u16* xb = (u16*)d_ws;                       // M*C
  u16* wqkvb = xb + (size_t)M * C;            // C3*C
  u16* wprojb = wqkvb + (size_t)C3 * C;       // C*C
  u16* qkvb = wprojb + (size_t)C * C;         // M*C3
  u16* vtb = qkvb + (size_t)M * C3;           // B*H*D*T = M*C
  u16* yb = vtb + (size_t)M * C;              // M*C

  cvt_f32_bf16<<<dim3((M * C) / 4 / 256), 256, 0, stream>>>(x, xb, (M * C) / 4);
  cvt_f32_bf16<<<dim3((C3 * C) / 4 / 256), 256, 0, stream>>>(Wqkv, wqkvb, (C3 * C) / 4);
  cvt_f32_bf16<<<dim3((C * C) / 4 / 256), 256, 0, stream>>>(Wproj, wprojb, (C * C) / 4);

  gemm_nt<1><<<dim3(C3 / 128, M / 128), 256, 0, stream>>>(xb, wqkvb, qkvb, M, C3, C);
  transpose_v<<<dim3(T / 64, B * H), 256, 0, stream>>>(qkvb, vtb);
  attn_fwd<<<dim3(512), 256, 0, stream>>>(qkvb, vtb, yb);
  gemm_nt<0><<<dim3(C / 128, M / 128), 256, 0, stream>>>(yb, wprojb, out, M, C, C);
}

// Round 9
// 115.373 us; speedup vs baseline: 1.1046x; 1.1046x over previous
//
#include <hip/hip_runtime.h>

typedef unsigned short u16;
typedef float f32x4 __attribute__((ext_vector_type(4)));
typedef __bf16 bf16x8 __attribute__((ext_vector_type(8)));
typedef unsigned int u32x4 __attribute__((ext_vector_type(4)));
typedef u16 u16x4 __attribute__((ext_vector_type(4)));
typedef u16 u16x8 __attribute__((ext_vector_type(8)));

static __device__ __forceinline__ u16 f2bf(float f) {
  union { __bf16 h; u16 u; } c;
  c.h = (__bf16)f;
  return c.u;
}

static __device__ __forceinline__ void gload_lds16(const void* g, void* l) {
  __builtin_amdgcn_global_load_lds(
      (const __attribute__((address_space(1))) unsigned int*)g,
      (__attribute__((address_space(3))) unsigned int*)l, 16, 0, 0);
}

// ---------------- fused fp32 -> bf16 convert (x, Wqkv, Wproj in one launch) ----------------
__global__ __launch_bounds__(256) void cvt3_f32_bf16(const float* __restrict__ a,
                                                     const float* __restrict__ bb,
                                                     const float* __restrict__ cc,
                                                     u16* __restrict__ out,
                                                     int n1, int n2, int n3) {
  int i = blockIdx.x * 256 + threadIdx.x;
  const float* src;
  int j = i;
  if (i < n1) { src = a; }
  else if (i < n1 + n2) { src = bb; j = i - n1; }
  else { src = cc; j = i - n1 - n2; if (j >= n3) return; }
  f32x4 v = *((const f32x4*)src + j);
  u16x4 o;
  o[0] = f2bf(v[0]); o[1] = f2bf(v[1]); o[2] = f2bf(v[2]); o[3] = f2bf(v[3]);
  *((u16x4*)out + i) = o;
}

// ---------------- GEMM: C[M,N] = A[M,K] * B[N,K]^T (bf16 in, fp32 acc) ----------------
// 128x128 tile, BK=64, 4 waves. global_load_lds w16 staging, both-sides swizzle.
// 1D grid, XCD-aware decode: xcd = bid&7 owns N/128/8 contiguous B-panels so
// B-tile re-reads (x M/128) hit that XCD's L2 (panel = 256KB << 4MB).
template<int OUT_BF16>
__global__ __launch_bounds__(256) void gemm_nt(const u16* __restrict__ A,
                                               const u16* __restrict__ B,
                                               void* __restrict__ Cp,
                                               int M, int N, int K, int gy) {
  __shared__ __align__(16) u16 lA[128 * 64];
  __shared__ __align__(16) u16 lB[128 * 64];
  const int tid = threadIdx.x;
  const int lane = tid & 63;
  const int wave = tid >> 6;
  const int wm = wave >> 1, wn = wave & 1;
  const int l15 = lane & 15, lg = lane >> 4;

  const int bid = blockIdx.x;
  const int xcd = bid & 7, s = bid >> 3;
  const int pnx = (N >> 7) >> 3;            // B-panels per XCD
  const int bm = (s % gy) * 128;
  const int bn = (xcd * pnx + s / gy) * 128;

  f32x4 acc[4][4];
#pragma unroll
  for (int i = 0; i < 4; ++i)
#pragma unroll
    for (int j = 0; j < 4; ++j) acc[i][j] = (f32x4){0.f, 0.f, 0.f, 0.f};

  const u16* Ag[4];
  const u16* Bg[4];
#pragma unroll
  for (int it = 0; it < 4; ++it) {
    const int ss = it * 256 + tid;
    const int row = ss >> 3, g = ss & 7;
    const int gsw = g ^ (row & 7);  // inverse swizzle on global source
    Ag[it] = A + (size_t)(bm + row) * K + gsw * 8;
    Bg[it] = B + (size_t)(bn + row) * K + gsw * 8;
  }

  for (int k0 = 0; k0 < K; k0 += 64) {
#pragma unroll
    for (int it = 0; it < 4; ++it) {
      gload_lds16(Ag[it] + k0, (u16*)lA + (size_t)(it * 256 + tid) * 8);
      gload_lds16(Bg[it] + k0, (u16*)lB + (size_t)(it * 256 + tid) * 8);
    }
    __syncthreads();
#pragma unroll
    for (int kk = 0; kk < 2; ++kk) {
      bf16x8 af[4], bfv[4];
#pragma unroll
      for (int mf = 0; mf < 4; ++mf) {
        const int row = wm * 64 + mf * 16 + l15;
        af[mf] = *(const bf16x8*)((const char*)lA + row * 128 +
                                  ((kk * 64 + lg * 16) ^ ((row & 7) << 4)));
      }
#pragma unroll
      for (int nf = 0; nf < 4; ++nf) {
        const int row = wn * 64 + nf * 16 + l15;
        bfv[nf] = *(const bf16x8*)((const char*)lB + row * 128 +
                                   ((kk * 64 + lg * 16) ^ ((row & 7) << 4)));
      }
#pragma unroll
      for (int mf = 0; mf < 4; ++mf)
#pragma unroll
        for (int nf = 0; nf < 4; ++nf)
          acc[mf][nf] = __builtin_amdgcn_mfma_f32_16x16x32_bf16(af[mf], bfv[nf], acc[mf][nf], 0, 0, 0);
    }
    __syncthreads();
  }

#pragma unroll
  for (int mf = 0; mf < 4; ++mf) {
#pragma unroll
    for (int r = 0; r < 4; ++r) {
      const int row = bm + wm * 64 + mf * 16 + lg * 4 + r;
#pragma unroll
      for (int nf = 0; nf < 4; ++nf) {
        const int col = bn + wn * 64 + nf * 16 + l15;
        const float v = acc[mf][nf][r];
        if (OUT_BF16) ((u16*)Cp)[(size_t)row * N + col] = f2bf(v);
        else          ((float*)Cp)[(size_t)row * N + col] = v;
      }
    }
  }
}

// ---------------- transpose V: qkv v-part [b,t,h,d] -> vt[bh][d][t] ----------------
__global__ __launch_bounds__(256) void transpose_v(const u16* __restrict__ qkv,
                                                   u16* __restrict__ vt) {
  constexpr int T = 2048, C3 = 3072, D = 64;
  __shared__ u16 lt[64 * 65];
  const int t0 = blockIdx.x * 64;
  const int bh = blockIdx.y;
  const int b = bh >> 4, h = bh & 15;
  const int tid = threadIdx.x;
#pragma unroll
  for (int it = 0; it < 2; ++it) {
    const int c = tid + it * 256;
    const int tr = c >> 3, d0 = (c & 7) * 8;
    u32x4 v = *(const u32x4*)&qkv[((size_t)b * T + t0 + tr) * C3 + 2048 + h * D + d0];
    const u16* pv = (const u16*)&v;
#pragma unroll
    for (int e = 0; e < 8; ++e) lt[tr * 65 + d0 + e] = pv[e];
  }
  __syncthreads();
#pragma unroll
  for (int it = 0; it < 2; ++it) {
    const int c = tid + it * 256;
    const int d = c >> 3, toff = (c & 7) * 8;
    u16x8 tmp;
#pragma unroll
    for (int e = 0; e < 8; ++e) tmp[e] = lt[(toff + e) * 65 + d];
    *(u16x8*)&vt[((size_t)bh * D + d) * T + t0 + toff] = tmp;
  }
}

// ---------------- flash attention fwd (causal), bf16 MFMA ----------------
// (Round-7 proven version) Paired (uniform 33 kv-iters/block), dbuf K/V
// (1 barrier/iter), 2-deep prefetch, XCD-aware 1D grid. Swapped QK^T
// (S = mfma(K,Q)): lane owns one q-row -> in-register row reduce + 2 shfl_xor.
// THR=0 defer-max (exact). Packed b64 P-store.
__global__ __launch_bounds__(256) void attn_fwd(const u16* __restrict__ qkv,
                                                const u16* __restrict__ vt,
                                                u16* __restrict__ y) {
  constexpr int T = 2048, C = 1024, C3 = 3072, D = 64, NQ = 32;
  __shared__ __align__(16) u16 lK[2][64 * 64];
  __shared__ __align__(16) u16 lV[2][64 * 64];
  __shared__ __align__(16) u16 lP[4 * 16 * 64];
  const int tid = threadIdx.x, lane = tid & 63, w = tid >> 6;
  const int l15 = lane & 15, lg = lane >> 4;

  const int bid = blockIdx.x;
  const int xcd = bid & 7, slot = bid >> 3;
  const int bh = xcd * 4 + (slot >> 4);
  const int pi = slot & 15;
  const int b = bh >> 4, h = bh & 15;

  const int r0 = tid >> 3, off0 = (tid & 7) * 8;
  const int r1 = (tid + 256) >> 3, off1 = off0;
  const int sb0 = (off0 * 2) ^ ((r0 & 7) << 4);
  const int sb1 = (off1 * 2) ^ ((r1 & 7) << 4);
  const u16* Kbase = qkv + (size_t)b * T * C3 + C + h * D;
  const u16* Vbase = vt + (size_t)bh * D * T;

  const float qscale = 0.125f * 1.44269504088896f;  // scale * log2(e)

#pragma unroll 1
  for (int qi = 0; qi < 2; ++qi) {
    const int qt = (qi == 0) ? pi : (NQ - 1 - pi);
    const int q0 = qt * 64;

    const size_t qoff = ((size_t)b * T + q0 + w * 16 + l15) * C3 + h * D;
    const bf16x8 aq0 = *(const bf16x8*)&qkv[qoff + lg * 8];
    const bf16x8 aq1 = *(const bf16x8*)&qkv[qoff + 32 + lg * 8];

    float m = -1.0e30f, l = 0.f;   // per-lane: this lane's q-row = w*16 + l15
    f32x4 o_acc[4];
#pragma unroll
    for (int nf = 0; nf < 4; ++nf) o_acc[nf] = (f32x4){0.f, 0.f, 0.f, 0.f};

    u32x4 rk0 = *(const u32x4*)(Kbase + (size_t)r0 * C3 + off0);
    u32x4 rk1 = *(const u32x4*)(Kbase + (size_t)r1 * C3 + off1);
    u32x4 rv0 = *(const u32x4*)(Vbase + (size_t)r0 * T + off0);
    u32x4 rv1 = *(const u32x4*)(Vbase + (size_t)r1 * T + off1);
    __syncthreads();
    *(u32x4*)&lK[0][(r0 * 128 + sb0) >> 1] = rk0;
    *(u32x4*)&lK[0][(r1 * 128 + sb1) >> 1] = rk1;
    *(u32x4*)&lV[0][(r0 * 128 + sb0) >> 1] = rv0;
    *(u32x4*)&lV[0][(r1 * 128 + sb1) >> 1] = rv1;
    if (qt > 0) {
      rk0 = *(const u32x4*)(Kbase + (size_t)(64 + r0) * C3 + off0);
      rk1 = *(const u32x4*)(Kbase + (size_t)(64 + r1) * C3 + off1);
      rv0 = *(const u32x4*)(Vbase + (size_t)r0 * T + 64 + off0);
      rv1 = *(const u32x4*)(Vbase + (size_t)r1 * T + 64 + off1);
    }

    for (int kt = 0; kt <= qt; ++kt) {
      const int cur = kt & 1;
      __syncthreads();
      if (kt < qt) {
        *(u32x4*)&lK[cur ^ 1][(r0 * 128 + sb0) >> 1] = rk0;
        *(u32x4*)&lK[cur ^ 1][(r1 * 128 + sb1) >> 1] = rk1;
        *(u32x4*)&lV[cur ^ 1][(r0 * 128 + sb0) >> 1] = rv0;
        *(u32x4*)&lV[cur ^ 1][(r1 * 128 + sb1) >> 1] = rv1;
        if (kt + 1 < qt) {
          const int kn = (kt + 2) * 64;
          rk0 = *(const u32x4*)(Kbase + (size_t)(kn + r0) * C3 + off0);
          rk1 = *(const u32x4*)(Kbase + (size_t)(kn + r1) * C3 + off1);
          rv0 = *(const u32x4*)(Vbase + (size_t)r0 * T + kn + off0);
          rv1 = *(const u32x4*)(Vbase + (size_t)r1 * T + kn + off1);
        }
      }
      const u16* Kc = lK[cur];
      const u16* Vc = lV[cur];

      f32x4 s[4];
#pragma unroll
      for (int nf = 0; nf < 4; ++nf) s[nf] = (f32x4){0.f, 0.f, 0.f, 0.f};
      __builtin_amdgcn_s_setprio(1);
#pragma unroll
      for (int nf = 0; nf < 4; ++nf) {
        const int row = nf * 16 + l15;
        const int x = (row & 7) << 4;
        bf16x8 bk0 = *(const bf16x8*)&Kc[(row * 128 + ((lg * 16) ^ x)) >> 1];
        bf16x8 bk1 = *(const bf16x8*)&Kc[(row * 128 + ((64 + lg * 16) ^ x)) >> 1];
        s[nf] = __builtin_amdgcn_mfma_f32_16x16x32_bf16(bk0, aq0, s[nf], 0, 0, 0);
        s[nf] = __builtin_amdgcn_mfma_f32_16x16x32_bf16(bk1, aq1, s[nf], 0, 0, 0);
      }
      __builtin_amdgcn_s_setprio(0);

#pragma unroll
      for (int nf = 0; nf < 4; ++nf) {
#pragma unroll
        for (int r = 0; r < 4; ++r) {
          float v = s[nf][r] * qscale;
          if (kt == qt) {
            if (nf * 16 + lg * 4 + r > w * 16 + l15) v = -1.0e30f;
          }
          s[nf][r] = v;
        }
      }

      float t0a = fmaxf(fmaxf(s[0][0], s[0][1]), fmaxf(s[0][2], s[0][3]));
      float t1a = fmaxf(fmaxf(s[1][0], s[1][1]), fmaxf(s[1][2], s[1][3]));
      float t2a = fmaxf(fmaxf(s[2][0], s[2][1]), fmaxf(s[2][2], s[2][3]));
      float t3a = fmaxf(fmaxf(s[3][0], s[3][1]), fmaxf(s[3][2], s[3][3]));
      float pmax = fmaxf(fmaxf(t0a, t1a), fmaxf(t2a, t3a));
      pmax = fmaxf(pmax, __shfl_xor(pmax, 16));
      pmax = fmaxf(pmax, __shfl_xor(pmax, 32));

      if (!__all(pmax <= m)) {
        const float mnew = fmaxf(m, pmax);
        const float fct = __builtin_amdgcn_exp2f(m - mnew);
        m = mnew;
        l *= fct;
#pragma unroll
        for (int r = 0; r < 4; ++r) {
          const float fr = __shfl(fct, lg * 4 + r);
#pragma unroll
          for (int nf = 0; nf < 4; ++nf) o_acc[nf][r] *= fr;
        }
      }

      float p[4][4];
#pragma unroll
      for (int nf = 0; nf < 4; ++nf)
#pragma unroll
        for (int r = 0; r < 4; ++r) p[nf][r] = __builtin_amdgcn_exp2f(s[nf][r] - m);
      float s0a = (p[0][0] + p[0][1]) + (p[0][2] + p[0][3]);
      float s1a = (p[1][0] + p[1][1]) + (p[1][2] + p[1][3]);
      float s2a = (p[2][0] + p[2][1]) + (p[2][2] + p[2][3]);
      float s3a = (p[3][0] + p[3][1]) + (p[3][2] + p[3][3]);
      float psum = (s0a + s1a) + (s2a + s3a);
      psum += __shfl_xor(psum, 16);
      psum += __shfl_xor(psum, 32);
      l += psum;

#pragma unroll
      for (int nf = 0; nf < 4; ++nf) {
        u16x4 pk;
        pk[0] = f2bf(p[nf][0]); pk[1] = f2bf(p[nf][1]);
        pk[2] = f2bf(p[nf][2]); pk[3] = f2bf(p[nf][3]);
        *(u16x4*)&lP[(w * 2048 + l15 * 128 + ((nf * 32 + lg * 8) ^ ((l15 & 7) << 4))) >> 1] = pk;
      }

      __builtin_amdgcn_s_setprio(1);
#pragma unroll
      for (int sj = 0; sj < 2; ++sj) {
        bf16x8 ap = *(const bf16x8*)&lP[(w * 2048 + l15 * 128 + ((sj * 64 + lg * 16) ^ ((l15 & 7) << 4))) >> 1];
#pragma unroll
        for (int nf = 0; nf < 4; ++nf) {
          const int d = nf * 16 + l15;
          bf16x8 bv = *(const bf16x8*)&Vc[(d * 128 + ((sj * 64 + lg * 16) ^ ((d & 7) << 4))) >> 1];
          o_acc[nf] = __builtin_amdgcn_mfma_f32_16x16x32_bf16(ap, bv, o_acc[nf], 0, 0, 0);
        }
      }
      __builtin_amdgcn_s_setprio(0);
    }

#pragma unroll
    for (int r = 0; r < 4; ++r) {
      const float li = __builtin_amdgcn_rcpf(__shfl(l, lg * 4 + r));
      const int row = q0 + w * 16 + lg * 4 + r;
#pragma unroll
      for (int nf = 0; nf < 4; ++nf) {
        const int col = h * D + nf * 16 + l15;
        y[((size_t)b * T + row) * C + col] = f2bf(o_acc[nf][r] * li);
      }
    }
  }
}

extern "C" void kernel_launch(void* const* d_in, const int* in_sizes, int n_in,
                              void* d_out, int out_size, void* d_ws, size_t ws_size,
                              hipStream_t stream) {
  const float* x = (const float*)d_in[0];
  const float* Wqkv = (const float*)d_in[1];
  const float* Wproj = (const float*)d_in[2];
  float* out = (float*)d_out;

  constexpr int B = 2, T = 2048, C = 1024, C3 = 3072, H = 16, D = 64;
  constexpr int M = B * T;  // 4096

  u16* xb = (u16*)d_ws;                       // M*C
  u16* wqkvb = xb + (size_t)M * C;            // C3*C
  u16* wprojb = wqkvb + (size_t)C3 * C;       // C*C
  u16* qkvb = wprojb + (size_t)C * C;         // M*C3
  u16* vtb = qkvb + (size_t)M * C3;           // B*H*D*T = M*C
  u16* yb = vtb + (size_t)M * C;              // M*C

  constexpr int n1 = (M * C) / 4, n2 = (C3 * C) / 4, n3 = (C * C) / 4;
  cvt3_f32_bf16<<<dim3((n1 + n2 + n3 + 255) / 256), 256, 0, stream>>>(
      x, Wqkv, Wproj, xb, n1, n2, n3);

  gemm_nt<1><<<dim3((C3 / 128) * (M / 128)), 256, 0, stream>>>(xb, wqkvb, qkvb, M, C3, C, M / 128);
  transpose_v<<<dim3(T / 64, B * H), 256, 0, stream>>>(qkvb, vtb);
  attn_fwd<<<dim3(512), 256, 0, stream>>>(qkvb, vtb, yb);
  gemm_nt<0><<<dim3((C / 128) * (M / 128)), 256, 0, stream>>>(yb, wprojb, out, M, C, C, M / 128);
}